// Round 6
// baseline (224.778 us; speedup 1.0000x reference)
//
#include <hip/hip_runtime.h>
#include <math.h>

// TiSASRec forward on MI355X — round 5:
//  - attn: one wave per query-PAIR {j,199-j} => every wave does exactly 201
//    keys (perfect balance), two interleaved streams (2x ILP), shared V loads
//  - Qt read direct from global (drops qt_s stage + its bank conflicts)
//  - embed fused into layer-0 ln_qkv; qt_kernel at 16 rows/block
// B=32, L=200, D=64, H=2, dh=32, NL=2.
#define BB 32
#define LLEN 200
#define DD 64
#define HH 2
#define NLAYER 2
#define BLD (BB * LLEN * DD)
#define TSPAN1 366   // TIME_SPAN+1

__device__ inline float waveSum(float v) {
#pragma unroll
    for (int off = 32; off > 0; off >>= 1) v += __shfl_xor(v, off);
    return v;
}
__device__ inline float halfSum(float v) {
    v += __shfl_xor(v, 1);
    v += __shfl_xor(v, 2);
    v += __shfl_xor(v, 4);
    v += __shfl_xor(v, 8);
    v += __shfl_xor(v, 16);
    return v;
}
__device__ inline float halfMax(float v) {
    v = fmaxf(v, __shfl_xor(v, 1));
    v = fmaxf(v, __shfl_xor(v, 2));
    v = fmaxf(v, __shfl_xor(v, 4));
    v = fmaxf(v, __shfl_xor(v, 8));
    v = fmaxf(v, __shfl_xor(v, 16));
    return v;
}

// grid=11: m<10 -> transpose 64x64 weights; m==10 -> transpose tK_emb to [64][366]
__global__ void transpose_kernel(const float* __restrict__ Wq,
                                 const float* __restrict__ Wk,
                                 const float* __restrict__ Wv,
                                 const float* __restrict__ W1,
                                 const float* __restrict__ W2,
                                 const float* __restrict__ tK_emb,
                                 float* __restrict__ wt,
                                 float* __restrict__ tKT) {
    int m = blockIdx.x;
    if (m < 10) {
        const float* src;
        switch (m % 5) {
            case 0: src = Wq; break;
            case 1: src = Wk; break;
            case 2: src = Wv; break;
            case 3: src = W1; break;
            default: src = W2; break;
        }
        src += (m / 5) * DD * DD;
        float* dst = wt + m * DD * DD;
        for (int e = threadIdx.x; e < DD * DD; e += 256) {
            int d = e >> 6, j = e & 63;
            dst[j * DD + d] = src[e];
        }
    } else {
        for (int e = threadIdx.x; e < TSPAN1 * DD; e += 256) {
            int t = e >> 6, d = e & 63;
            tKT[d * TSPAN1 + t] = tK_emb[e];
        }
    }
}

// 4 rows/block, wave per row. Layer 0 (first=1) gathers the embedding
// directly (x never materialized). q=LN(xin); Q=q@WqT+bq; K,V likewise +pos.
__global__ void ln_qkv_kernel(const float* __restrict__ x,
                              const int* __restrict__ log_ids,
                              const float* __restrict__ item_emb,
                              int first,
                              const float* __restrict__ g,
                              const float* __restrict__ bln,
                              const float* __restrict__ WqT, const float* __restrict__ bq,
                              const float* __restrict__ WkT, const float* __restrict__ bk,
                              const float* __restrict__ WvT, const float* __restrict__ bv,
                              const float* __restrict__ posK,
                              const float* __restrict__ posV,
                              float* __restrict__ q,
                              float* __restrict__ Q, float* __restrict__ K,
                              float* __restrict__ V) {
    __shared__ float qs[4][DD], xs[4][DD];
    int tid = threadIdx.x;
    int wid = tid >> 6, d = tid & 63;
    int row = blockIdx.x * 4 + wid;
    int l = row % LLEN;
    float xv;
    if (first) {
        int id = log_ids[row];
        xv = (id == 0) ? 0.0f : item_emb[id * DD + d] * 8.0f;  // *sqrt(64)*keep
    } else {
        xv = x[row * DD + d];
    }
    xs[wid][d] = xv;
    float m = waveSum(xv) * (1.0f / 64.0f);
    float c = xv - m;
    float var = waveSum(c * c) * (1.0f / 64.0f);
    float qv = (c / sqrtf(var + 1e-8f)) * g[d] + bln[d];
    qs[wid][d] = qv;
    q[row * DD + d] = qv;
    // per-wave LDS region; wave-lockstep + compiler lgkmcnt makes this safe
    float aq = bq[d], ak = bk[d], av = bv[d];
#pragma unroll 8
    for (int j = 0; j < DD; ++j) {
        aq = fmaf(qs[wid][j], WqT[j * DD + d], aq);
        ak = fmaf(xs[wid][j], WkT[j * DD + d], ak);
        av = fmaf(xs[wid][j], WvT[j * DD + d], av);
    }
    Q[row * DD + d] = aq;
    K[row * DD + d] = ak + posK[l * DD + d];
    V[row * DD + d] = av + posV[l * DD + d];
}

// Qt[row][h][t] = sum_d Qh[row][h*32+d] * tK_emb[t][h*32+d]
// 16 rows per block, 384 threads (thread t<366 owns one t).
__global__ void qt_kernel(const float* __restrict__ Q,
                          const float* __restrict__ tKT,
                          float* __restrict__ Qt_g) {
    __shared__ float Qs[16][DD];
    int tid = threadIdx.x;
    int base = blockIdx.x * 16;
    for (int e = tid; e < 16 * DD; e += 384)
        Qs[e >> 6][e & 63] = Q[(base + (e >> 6)) * DD + (e & 63)];
    __syncthreads();
    int t = tid;
    if (t < TSPAN1) {
        float acc[16];
#pragma unroll
        for (int gg = 0; gg < 16; ++gg) acc[gg] = 0.0f;
        for (int d = 0; d < 32; ++d) {
            float v = tKT[d * TSPAN1 + t];
#pragma unroll
            for (int gg = 0; gg < 16; ++gg) acc[gg] = fmaf(v, Qs[gg][d], acc[gg]);
        }
#pragma unroll
        for (int gg = 0; gg < 16; ++gg)
            Qt_g[(base + gg) * (2 * TSPAN1) + t] = acc[gg];
#pragma unroll
        for (int gg = 0; gg < 16; ++gg) acc[gg] = 0.0f;
        for (int d = 32; d < 64; ++d) {
            float v = tKT[d * TSPAN1 + t];
#pragma unroll
            for (int gg = 0; gg < 16; ++gg) acc[gg] = fmaf(v, Qs[gg][d], acc[gg]);
        }
#pragma unroll
        for (int gg = 0; gg < 16; ++gg)
            Qt_g[(base + gg) * (2 * TSPAN1) + TSPAN1 + t] = acc[gg];
    }
}

// Attention: one wave per query-pair {j, 199-j} -> every wave processes
// exactly 201 keys. Two interleaved streams (a=short, b=long). Phases are
// per-wave (no inter-phase barriers). grid = B*25, block = 256 (4 waves).
__global__ void attn_kernel(const float* __restrict__ Q,
                            const float* __restrict__ Keff,
                            const float* __restrict__ Veff,
                            const int* __restrict__ log_times,
                            const float* __restrict__ Qt_g,
                            const float* __restrict__ tV_emb,
                            float* __restrict__ out) {
    __shared__ int t_s[LLEN];
    __shared__ float sc[4][2][HH][LLEN];        // [wave][pair-sel][head][key]
    __shared__ unsigned short tm[4][2][LLEN];

    int tid = threadIdx.x;
    int wid = tid >> 6;
    int lane = tid & 63;
    int bi = blockIdx.x / 25;
    int j = (blockIdx.x % 25) * 4 + wid;        // 0..99
    int qa = j, qb = 199 - j;
    int rowa = bi * LLEN + qa, rowb = bi * LLEN + qb;
    int lena = qa + 1, lenb = qb + 1;           // lena <= 100 < lenb

    if (tid < LLEN) t_s[tid] = log_times[bi * LLEN + tid];
    __syncthreads();

    // bucket tables for both queries (per-wave LDS region)
    {
        int tqa = t_s[qa], tqb = t_s[qb];
        for (int k = lane; k < lenb; k += 64) {
            int tk = t_s[k];
            int dta = tqa - tk; if (dta < 0) dta = -dta;
            int dtb = tqb - tk; if (dtb < 0) dtb = -dtb;
            if (k < lena)
                tm[wid][0][k] = (unsigned short)(int)fminf((float)dta * (1.0f / 86400.0f), 365.0f);
            tm[wid][1][k] = (unsigned short)(int)fminf((float)dtb * (1.0f / 86400.0f), 365.0f);
        }
    }

    int h = lane >> 5;       // head
    int l5 = lane & 31;
    int cch = l5 >> 2;       // channel chunk 0..7
    int jo = l5 & 3;         // key offset in group
    float4 qva = ((const float4*)(Q + rowa * DD))[h * 8 + cch];
    float4 qvb = ((const float4*)(Q + rowb * DD))[h * 8 + cch];
    const float4* K4 = (const float4*)(Keff + bi * LLEN * DD);
    const float* qta = Qt_g + rowa * (2 * TSPAN1) + h * TSPAN1;
    const float* qtb = Qt_g + rowb * (2 * TSPAN1) + h * TSPAN1;
    const float scale = 0.17677669529663687f;   // 1/sqrt(32)

    // phase 1: scores, 4 keys/group, both streams interleaved while k<lena
    int k0 = 0;
    for (; k0 < lena; k0 += 4) {
        int k = k0 + jo;
        int ka = (k < lena) ? k : (lena - 1);
        int kb = (k < lenb) ? k : (lenb - 1);
        int ba = tm[wid][0][ka], bb2 = tm[wid][1][kb];
        float4 kva = K4[ka * 16 + h * 8 + cch];
        float4 kvb = K4[kb * 16 + h * 8 + cch];
        float pa = qva.x * kva.x + qva.y * kva.y + qva.z * kva.z + qva.w * kva.w;
        float pb = qvb.x * kvb.x + qvb.y * kvb.y + qvb.z * kvb.z + qvb.w * kvb.w;
        pa += __shfl_xor(pa, 4);  pb += __shfl_xor(pb, 4);
        pa += __shfl_xor(pa, 8);  pb += __shfl_xor(pb, 8);
        pa += __shfl_xor(pa, 16); pb += __shfl_xor(pb, 16);
        float sa = (pa + qta[ba]) * scale;
        float sb = (pb + qtb[bb2]) * scale;
        if (cch == 0) {
            if (k < lena) sc[wid][0][h][k] = sa;
            if (k < lenb) sc[wid][1][h][k] = sb;
        }
    }
    for (; k0 < lenb; k0 += 4) {
        int k = k0 + jo;
        int kb = (k < lenb) ? k : (lenb - 1);
        int bb2 = tm[wid][1][kb];
        float4 kvb = K4[kb * 16 + h * 8 + cch];
        float pb = qvb.x * kvb.x + qvb.y * kvb.y + qvb.z * kvb.z + qvb.w * kvb.w;
        pb += __shfl_xor(pb, 4);
        pb += __shfl_xor(pb, 8);
        pb += __shfl_xor(pb, 16);
        float sb = (pb + qtb[bb2]) * scale;
        if (cch == 0 && k < lenb) sc[wid][1][h][k] = sb;
    }

    // phase 2: softmax x2 (lanes 0..31 head 0, 32..63 head 1; same wave)
#pragma unroll
    for (int qsel = 0; qsel < 2; ++qsel) {
        int len = qsel ? lenb : lena;
        float* srow = sc[wid][qsel][h];
        float m = -INFINITY;
        for (int k = l5; k < len; k += 32) m = fmaxf(m, srow[k]);
        m = halfMax(m);
        float s = 0.0f;
        for (int k = l5; k < len; k += 32) {
            float e = expf(srow[k] - m);
            srow[k] = e;
            s += e;
        }
        s = halfSum(s);
        float inv = 1.0f / s;
        for (int k = l5; k < len; k += 32) srow[k] *= inv;
    }

    // phase 3: out[d] = sum_k A[k]*(V[k][d] + tV[bucket][d]); V load shared
    const float* Vb = Veff + bi * LLEN * DD + lane;
    const float* tVl = tV_emb + lane;
    float aA0 = 0, aA1 = 0, aA2 = 0, aA3 = 0;
    float aB0 = 0, aB1 = 0, aB2 = 0, aB3 = 0;
    int k = 0;
    for (; k + 4 <= lena; k += 4) {
        float v0 = Vb[(k + 0) * DD], v1 = Vb[(k + 1) * DD];
        float v2 = Vb[(k + 2) * DD], v3 = Vb[(k + 3) * DD];
        aA0 = fmaf(sc[wid][0][h][k + 0], v0 + tVl[tm[wid][0][k + 0] * DD], aA0);
        aB0 = fmaf(sc[wid][1][h][k + 0], v0 + tVl[tm[wid][1][k + 0] * DD], aB0);
        aA1 = fmaf(sc[wid][0][h][k + 1], v1 + tVl[tm[wid][0][k + 1] * DD], aA1);
        aB1 = fmaf(sc[wid][1][h][k + 1], v1 + tVl[tm[wid][1][k + 1] * DD], aB1);
        aA2 = fmaf(sc[wid][0][h][k + 2], v2 + tVl[tm[wid][0][k + 2] * DD], aA2);
        aB2 = fmaf(sc[wid][1][h][k + 2], v2 + tVl[tm[wid][1][k + 2] * DD], aB2);
        aA3 = fmaf(sc[wid][0][h][k + 3], v3 + tVl[tm[wid][0][k + 3] * DD], aA3);
        aB3 = fmaf(sc[wid][1][h][k + 3], v3 + tVl[tm[wid][1][k + 3] * DD], aB3);
    }
    for (; k < lena; ++k) {
        float vv = Vb[k * DD];
        aA0 = fmaf(sc[wid][0][h][k], vv + tVl[tm[wid][0][k] * DD], aA0);
        aB0 = fmaf(sc[wid][1][h][k], vv + tVl[tm[wid][1][k] * DD], aB0);
    }
    for (; k + 4 <= lenb; k += 4) {
        aB0 = fmaf(sc[wid][1][h][k + 0], Vb[(k + 0) * DD] + tVl[tm[wid][1][k + 0] * DD], aB0);
        aB1 = fmaf(sc[wid][1][h][k + 1], Vb[(k + 1) * DD] + tVl[tm[wid][1][k + 1] * DD], aB1);
        aB2 = fmaf(sc[wid][1][h][k + 2], Vb[(k + 2) * DD] + tVl[tm[wid][1][k + 2] * DD], aB2);
        aB3 = fmaf(sc[wid][1][h][k + 3], Vb[(k + 3) * DD] + tVl[tm[wid][1][k + 3] * DD], aB3);
    }
    for (; k < lenb; ++k)
        aB0 = fmaf(sc[wid][1][h][k], Vb[k * DD] + tVl[tm[wid][1][k] * DD], aB0);

    out[rowa * DD + lane] = (aA0 + aA1) + (aA2 + aA3);
    out[rowb * DD + lane] = (aB0 + aB1) + (aB2 + aB3);
}

// 4 rows/block: x = LN(q+att); x = (x + relu(x@W1T+b1)@W2T + b2) * keep
__global__ void addln_ffn_kernel(const float* __restrict__ qin,
                                 const float* __restrict__ att,
                                 const float* __restrict__ g,
                                 const float* __restrict__ bln,
                                 const float* __restrict__ W1T, const float* __restrict__ b1,
                                 const float* __restrict__ W2T, const float* __restrict__ b2,
                                 const int* __restrict__ log_ids,
                                 float* __restrict__ xout) {
    __shared__ float xs[4][DD], hs[4][DD];
    int tid = threadIdx.x;
    int wid = tid >> 6, d = tid & 63;
    int row = blockIdx.x * 4 + wid;
    float v = qin[row * DD + d] + att[row * DD + d];
    float m = waveSum(v) * (1.0f / 64.0f);
    float c = v - m;
    float var = waveSum(c * c) * (1.0f / 64.0f);
    float xv = (c / sqrtf(var + 1e-8f)) * g[d] + bln[d];
    xs[wid][d] = xv;
    float a = b1[d];
#pragma unroll 8
    for (int j = 0; j < DD; ++j) a = fmaf(xs[wid][j], W1T[j * DD + d], a);
    hs[wid][d] = fmaxf(a, 0.0f);
    float o = b2[d];
#pragma unroll 8
    for (int j = 0; j < DD; ++j) o = fmaf(hs[wid][j], W2T[j * DD + d], o);
    float res = xv + o;
    if (log_ids[row] == 0) res = 0.0f;
    xout[row * DD + d] = res;
}

// 4 rows/block: feats = LN(x); logits = dot(feats, item_emb[pos/neg])
__global__ void final_kernel(const float* __restrict__ x,
                             const float* __restrict__ g,
                             const float* __restrict__ b,
                             const float* __restrict__ item_emb,
                             const int* __restrict__ pos_ids,
                             const int* __restrict__ neg_ids,
                             float* __restrict__ out) {
    int tid = threadIdx.x;
    int wid = tid >> 6, d = tid & 63;
    int row = blockIdx.x * 4 + wid;
    float v = x[row * DD + d];
    float m = waveSum(v) * (1.0f / 64.0f);
    float c = v - m;
    float var = waveSum(c * c) * (1.0f / 64.0f);
    float f = (c / sqrtf(var + 1e-8f)) * g[d] + b[d];
    int pid = pos_ids[row];
    int nid = neg_ids[row];
    float p = waveSum(f * item_emb[pid * DD + d]);
    float n = waveSum(f * item_emb[nid * DD + d]);
    if (d == 0) {
        out[row] = p;
        out[BB * LLEN + row] = n;
    }
}

extern "C" void kernel_launch(void* const* d_in, const int* in_sizes, int n_in,
                              void* d_out, int out_size, void* d_ws, size_t ws_size,
                              hipStream_t stream) {
    const int* log_ids = (const int*)d_in[0];
    const int* log_times = (const int*)d_in[1];
    const int* pos_ids = (const int*)d_in[2];
    const int* neg_ids = (const int*)d_in[3];
    const float* item_emb = (const float*)d_in[4];
    const float* posK = (const float*)d_in[5];
    const float* posV = (const float*)d_in[6];
    const float* tK_emb = (const float*)d_in[7];
    const float* tV_emb = (const float*)d_in[8];
    const float* ln1_g = (const float*)d_in[9];
    const float* ln1_b = (const float*)d_in[10];
    const float* Wq = (const float*)d_in[11];
    const float* bq = (const float*)d_in[12];
    const float* Wk = (const float*)d_in[13];
    const float* bk = (const float*)d_in[14];
    const float* Wv = (const float*)d_in[15];
    const float* bv = (const float*)d_in[16];
    const float* ln2_g = (const float*)d_in[17];
    const float* ln2_b = (const float*)d_in[18];
    const float* W1 = (const float*)d_in[19];
    const float* b1 = (const float*)d_in[20];
    const float* W2 = (const float*)d_in[21];
    const float* b2 = (const float*)d_in[22];
    const float* lnf_g = (const float*)d_in[23];
    const float* lnf_b = (const float*)d_in[24];

    float* ws = (float*)d_ws;
    float* x = ws;                        // [B,L,D] (inter-layer)
    float* q = x + BLD;
    float* Qb = q + BLD;
    float* Kb = Qb + BLD;
    float* Vb = Kb + BLD;
    float* att = Vb + BLD;
    float* wt = att + BLD;                // 10 x 64x64 transposed weights
    float* tKT = wt + 10 * DD * DD;       // [64][366]
    float* Qt = tKT + DD * TSPAN1;        // [6400][732]

    const int nrow = BB * LLEN;           // 6400

    transpose_kernel<<<11, 256, 0, stream>>>(Wq, Wk, Wv, W1, W2, tK_emb, wt, tKT);

    for (int i = 0; i < NLAYER; ++i) {
        const float* WqT = wt + (i * 5 + 0) * DD * DD;
        const float* WkT = wt + (i * 5 + 1) * DD * DD;
        const float* WvT = wt + (i * 5 + 2) * DD * DD;
        const float* W1T = wt + (i * 5 + 3) * DD * DD;
        const float* W2T = wt + (i * 5 + 4) * DD * DD;
        ln_qkv_kernel<<<nrow / 4, 256, 0, stream>>>(x, log_ids, item_emb, (i == 0),
                                                    ln1_g + i * DD, ln1_b + i * DD,
                                                    WqT, bq + i * DD,
                                                    WkT, bk + i * DD,
                                                    WvT, bv + i * DD,
                                                    posK, posV,
                                                    q, Qb, Kb, Vb);
        qt_kernel<<<nrow / 16, 384, 0, stream>>>(Qb, tKT, Qt);
        attn_kernel<<<BB * 25, 256, 0, stream>>>(Qb, Kb, Vb, log_times,
                                                 Qt, tV_emb, att);
        addln_ffn_kernel<<<nrow / 4, 256, 0, stream>>>(q, att, ln2_g + i * DD,
                                                       ln2_b + i * DD,
                                                       W1T, b1 + i * DD,
                                                       W2T, b2 + i * DD,
                                                       log_ids, x);
    }

    final_kernel<<<nrow / 4, 256, 0, stream>>>(x, lnf_g, lnf_b, item_emb,
                                               pos_ids, neg_ids, (float*)d_out);
}

// Round 7
// 198.358 us; speedup vs baseline: 1.1332x; 1.1332x over previous
//
#include <hip/hip_runtime.h>
#include <math.h>

// TiSASRec forward on MI355X — round 6:
//  - attn reverted to R4 structure (one query/wave, 4-key groups) — R5's
//    pairing halved TLP and regressed; keep R5's direct-Qt-global read
//    (kills qt_s stage: LDS 21->8.8KB, bank conflicts -> 0)
//  - layer-boundary fusion: MID = addln_ffn(L0)+ln_qkv(L1),
//    END = addln_ffn(L1)+final. 8 launches total.
// B=32, L=200, D=64, H=2, dh=32, NL=2.
#define BB 32
#define LLEN 200
#define DD 64
#define HH 2
#define NLAYER 2
#define BLD (BB * LLEN * DD)
#define TSPAN1 366   // TIME_SPAN+1

__device__ inline float waveSum(float v) {
#pragma unroll
    for (int off = 32; off > 0; off >>= 1) v += __shfl_xor(v, off);
    return v;
}
__device__ inline float halfSum(float v) {
    v += __shfl_xor(v, 1);
    v += __shfl_xor(v, 2);
    v += __shfl_xor(v, 4);
    v += __shfl_xor(v, 8);
    v += __shfl_xor(v, 16);
    return v;
}
__device__ inline float halfMax(float v) {
    v = fmaxf(v, __shfl_xor(v, 1));
    v = fmaxf(v, __shfl_xor(v, 2));
    v = fmaxf(v, __shfl_xor(v, 4));
    v = fmaxf(v, __shfl_xor(v, 8));
    v = fmaxf(v, __shfl_xor(v, 16));
    return v;
}

// grid=11: m<10 -> transpose 64x64 weights; m==10 -> tK_emb^T [64][366]
__global__ void transpose_kernel(const float* __restrict__ Wq,
                                 const float* __restrict__ Wk,
                                 const float* __restrict__ Wv,
                                 const float* __restrict__ W1,
                                 const float* __restrict__ W2,
                                 const float* __restrict__ tK_emb,
                                 float* __restrict__ wt,
                                 float* __restrict__ tKT) {
    int m = blockIdx.x;
    if (m < 10) {
        const float* src;
        switch (m % 5) {
            case 0: src = Wq; break;
            case 1: src = Wk; break;
            case 2: src = Wv; break;
            case 3: src = W1; break;
            default: src = W2; break;
        }
        src += (m / 5) * DD * DD;
        float* dst = wt + m * DD * DD;
        for (int e = threadIdx.x; e < DD * DD; e += 256) {
            int d = e >> 6, j = e & 63;
            dst[j * DD + d] = src[e];
        }
    } else {
        for (int e = threadIdx.x; e < TSPAN1 * DD; e += 256) {
            int t = e >> 6, d = e & 63;
            tKT[d * TSPAN1 + t] = tK_emb[e];
        }
    }
}

// Layer-0 entry: 4 rows/block, wave per row. Embedding gather fused
// (first layer only). q=LN(x); Q=q@WqT+bq; K,V likewise + pos fold.
__global__ void ln_qkv_kernel(const int* __restrict__ log_ids,
                              const float* __restrict__ item_emb,
                              const float* __restrict__ g,
                              const float* __restrict__ bln,
                              const float* __restrict__ WqT, const float* __restrict__ bq,
                              const float* __restrict__ WkT, const float* __restrict__ bk,
                              const float* __restrict__ WvT, const float* __restrict__ bv,
                              const float* __restrict__ posK,
                              const float* __restrict__ posV,
                              float* __restrict__ q,
                              float* __restrict__ Q, float* __restrict__ K,
                              float* __restrict__ V) {
    __shared__ float qs[4][DD], xs[4][DD];
    int tid = threadIdx.x;
    int wid = tid >> 6, d = tid & 63;
    int row = blockIdx.x * 4 + wid;
    int l = row % LLEN;
    int id = log_ids[row];
    float xv = (id == 0) ? 0.0f : item_emb[id * DD + d] * 8.0f;  // sqrt(64)*keep
    xs[wid][d] = xv;
    float m = waveSum(xv) * (1.0f / 64.0f);
    float c = xv - m;
    float var = waveSum(c * c) * (1.0f / 64.0f);
    float qv = (c / sqrtf(var + 1e-8f)) * g[d] + bln[d];
    qs[wid][d] = qv;
    q[row * DD + d] = qv;
    // per-wave LDS region; wave-lockstep + compiler lgkmcnt makes this safe
    float aq = bq[d], ak = bk[d], av = bv[d];
#pragma unroll 8
    for (int j = 0; j < DD; ++j) {
        aq = fmaf(qs[wid][j], WqT[j * DD + d], aq);
        ak = fmaf(xs[wid][j], WkT[j * DD + d], ak);
        av = fmaf(xs[wid][j], WvT[j * DD + d], av);
    }
    Q[row * DD + d] = aq;
    K[row * DD + d] = ak + posK[l * DD + d];
    V[row * DD + d] = av + posV[l * DD + d];
}

// Qt[row][h*366+t] = sum_d Qh[row][h*32+d] * tK_emb[t][h*32+d]
// 16 rows per block, 384 threads (thread t<366 owns one t).
__global__ void qt_kernel(const float* __restrict__ Q,
                          const float* __restrict__ tKT,
                          float* __restrict__ Qt_g) {
    __shared__ float Qs[16][DD];
    int tid = threadIdx.x;
    int base = blockIdx.x * 16;
    for (int e = tid; e < 16 * DD; e += 384)
        Qs[e >> 6][e & 63] = Q[(base + (e >> 6)) * DD + (e & 63)];
    __syncthreads();
    int t = tid;
    if (t < TSPAN1) {
        float acc[16];
#pragma unroll
        for (int gg = 0; gg < 16; ++gg) acc[gg] = 0.0f;
        for (int d = 0; d < 32; ++d) {
            float v = tKT[d * TSPAN1 + t];
#pragma unroll
            for (int gg = 0; gg < 16; ++gg) acc[gg] = fmaf(v, Qs[gg][d], acc[gg]);
        }
#pragma unroll
        for (int gg = 0; gg < 16; ++gg)
            Qt_g[(base + gg) * (2 * TSPAN1) + t] = acc[gg];
#pragma unroll
        for (int gg = 0; gg < 16; ++gg) acc[gg] = 0.0f;
        for (int d = 32; d < 64; ++d) {
            float v = tKT[d * TSPAN1 + t];
#pragma unroll
            for (int gg = 0; gg < 16; ++gg) acc[gg] = fmaf(v, Qs[gg][d], acc[gg]);
        }
#pragma unroll
        for (int gg = 0; gg < 16; ++gg)
            Qt_g[(base + gg) * (2 * TSPAN1) + TSPAN1 + t] = acc[gg];
    }
}

// Attention: wave-per-query {i,99-i,100+i,199-i}; per-wave phases (no
// inter-phase barriers); 4-key score groups (float4 K, 3-shfl reduce);
// Qt read direct from global (L1-hot per-row). grid = B*50, block 256.
__global__ void attn_kernel(const float* __restrict__ Q,
                            const float* __restrict__ Keff,
                            const float* __restrict__ Veff,
                            const int* __restrict__ log_times,
                            const float* __restrict__ Qt_g,
                            const float* __restrict__ tV_emb,
                            float* __restrict__ out) {
    __shared__ int t_s[LLEN];
    __shared__ float sc[4][HH][LLEN];
    __shared__ unsigned short tm_s[4][LLEN];

    int tid = threadIdx.x;
    int wid = tid >> 6;
    int lane = tid & 63;
    int bi = blockIdx.x / 50;
    int i = blockIdx.x % 50;
    int qi = (wid == 0) ? i : (wid == 1) ? (99 - i) : (wid == 2) ? (100 + i) : (199 - i);
    int row = bi * LLEN + qi;
    int len = qi + 1;

    if (tid < LLEN) t_s[tid] = log_times[bi * LLEN + tid];
    __syncthreads();

    // bucket table for this query (per-wave LDS region)
    int tq = t_s[qi];
    for (int k = lane; k < len; k += 64) {
        int dt = tq - t_s[k];
        if (dt < 0) dt = -dt;
        float dtf = fminf((float)dt * (1.0f / 86400.0f), 365.0f);
        tm_s[wid][k] = (unsigned short)(int)dtf;
    }

    int h = lane >> 5;       // head
    int l5 = lane & 31;
    int cch = l5 >> 2;       // channel chunk 0..7
    int jo = l5 & 3;         // key offset in group
    float4 qv = ((const float4*)(Q + row * DD))[h * 8 + cch];
    const float4* K4 = (const float4*)(Keff + bi * LLEN * DD);
    const float* qtrow = Qt_g + row * (2 * TSPAN1) + h * TSPAN1;
    const float scale = 0.17677669529663687f;  // 1/sqrt(32)

    // phase 1: scores, 4 keys per iteration
    for (int k0 = 0; k0 < len; k0 += 4) {
        int k = k0 + jo;
        int kc = (k < len) ? k : (len - 1);
        int bucket = tm_s[wid][kc];
        float4 kv = K4[kc * 16 + h * 8 + cch];
        float p = qv.x * kv.x + qv.y * kv.y + qv.z * kv.z + qv.w * kv.w;
        p += __shfl_xor(p, 4);
        p += __shfl_xor(p, 8);
        p += __shfl_xor(p, 16);   // full 32-dot for (h, key k)
        float s = (p + qtrow[bucket]) * scale;
        if (cch == 0 && k < len) sc[wid][h][k] = s;
    }

    // phase 2: softmax (lanes 0..31 head 0, 32..63 head 1; same wave)
    {
        float m = -INFINITY;
        for (int k = l5; k < len; k += 32) m = fmaxf(m, sc[wid][h][k]);
        m = halfMax(m);
        float s = 0.0f;
        for (int k = l5; k < len; k += 32) {
            float e = expf(sc[wid][h][k] - m);
            sc[wid][h][k] = e;
            s += e;
        }
        s = halfSum(s);
        float inv = 1.0f / s;
        for (int k = l5; k < len; k += 32) sc[wid][h][k] *= inv;
    }

    // phase 3: out[d] = sum_k A[h][k] * (V_eff[k][d] + tV[bucket[k]][d])
    const float* Vb = Veff + bi * LLEN * DD + lane;
    const float* tVl = tV_emb + lane;
    float acc0 = 0.0f, acc1 = 0.0f, acc2 = 0.0f, acc3 = 0.0f;
    int k = 0;
    for (; k + 4 <= len; k += 4) {
        int b0 = tm_s[wid][k + 0];
        int b1 = tm_s[wid][k + 1];
        int b2 = tm_s[wid][k + 2];
        int b3 = tm_s[wid][k + 3];
        float a0 = sc[wid][h][k + 0];
        float a1 = sc[wid][h][k + 1];
        float a2 = sc[wid][h][k + 2];
        float a3 = sc[wid][h][k + 3];
        acc0 = fmaf(a0, Vb[(k + 0) * DD] + tVl[b0 * DD], acc0);
        acc1 = fmaf(a1, Vb[(k + 1) * DD] + tVl[b1 * DD], acc1);
        acc2 = fmaf(a2, Vb[(k + 2) * DD] + tVl[b2 * DD], acc2);
        acc3 = fmaf(a3, Vb[(k + 3) * DD] + tVl[b3 * DD], acc3);
    }
    for (; k < len; ++k) {
        int b0 = tm_s[wid][k];
        acc0 = fmaf(sc[wid][h][k], Vb[k * DD] + tVl[b0 * DD], acc0);
    }
    out[row * DD + lane] = (acc0 + acc1) + (acc2 + acc3);
}

// MID: addln_ffn(layer i) fused with ln_qkv(layer i+1). 4 rows/block.
__global__ void mid_kernel(const float* __restrict__ qin,
                           const float* __restrict__ att,
                           const float* __restrict__ g2, const float* __restrict__ b2ln,
                           const float* __restrict__ W1T, const float* __restrict__ b1v,
                           const float* __restrict__ W2T, const float* __restrict__ b2v,
                           const int* __restrict__ log_ids,
                           const float* __restrict__ g1n, const float* __restrict__ b1n,
                           const float* __restrict__ WqT, const float* __restrict__ bq,
                           const float* __restrict__ WkT, const float* __restrict__ bk,
                           const float* __restrict__ WvT, const float* __restrict__ bv,
                           const float* __restrict__ posK,
                           const float* __restrict__ posV,
                           float* __restrict__ q,
                           float* __restrict__ Q, float* __restrict__ K,
                           float* __restrict__ V) {
    __shared__ float xs[4][DD], hs[4][DD], qs[4][DD];
    int tid = threadIdx.x;
    int wid = tid >> 6, d = tid & 63;
    int row = blockIdx.x * 4 + wid;
    int l = row % LLEN;
    // --- addln + FFN ---
    float v = qin[row * DD + d] + att[row * DD + d];
    float m = waveSum(v) * (1.0f / 64.0f);
    float c = v - m;
    float var = waveSum(c * c) * (1.0f / 64.0f);
    float xv = (c / sqrtf(var + 1e-8f)) * g2[d] + b2ln[d];
    xs[wid][d] = xv;
    float a = b1v[d];
#pragma unroll 8
    for (int j = 0; j < DD; ++j) a = fmaf(xs[wid][j], W1T[j * DD + d], a);
    hs[wid][d] = fmaxf(a, 0.0f);
    float o = b2v[d];
#pragma unroll 8
    for (int j = 0; j < DD; ++j) o = fmaf(hs[wid][j], W2T[j * DD + d], o);
    float res = xv + o;
    if (log_ids[row] == 0) res = 0.0f;
    // --- next layer: LN1 + QKV projection ---
    float m2 = waveSum(res) * (1.0f / 64.0f);
    float c2 = res - m2;
    float var2 = waveSum(c2 * c2) * (1.0f / 64.0f);
    float qv = (c2 / sqrtf(var2 + 1e-8f)) * g1n[d] + b1n[d];
    qs[wid][d] = qv;
    xs[wid][d] = res;     // xs reuse: a-loop above already consumed old xs
    q[row * DD + d] = qv;
    float aq = bq[d], ak = bk[d], av = bv[d];
#pragma unroll 8
    for (int j = 0; j < DD; ++j) {
        aq = fmaf(qs[wid][j], WqT[j * DD + d], aq);
        ak = fmaf(xs[wid][j], WkT[j * DD + d], ak);
        av = fmaf(xs[wid][j], WvT[j * DD + d], av);
    }
    Q[row * DD + d] = aq;
    K[row * DD + d] = ak + posK[l * DD + d];
    V[row * DD + d] = av + posV[l * DD + d];
}

// END: addln_ffn(last layer) fused with final LN + logits. 4 rows/block.
__global__ void end_kernel(const float* __restrict__ qin,
                           const float* __restrict__ att,
                           const float* __restrict__ g2, const float* __restrict__ b2ln,
                           const float* __restrict__ W1T, const float* __restrict__ b1v,
                           const float* __restrict__ W2T, const float* __restrict__ b2v,
                           const int* __restrict__ log_ids,
                           const float* __restrict__ lnf_g, const float* __restrict__ lnf_b,
                           const float* __restrict__ item_emb,
                           const int* __restrict__ pos_ids,
                           const int* __restrict__ neg_ids,
                           float* __restrict__ out) {
    __shared__ float xs[4][DD], hs[4][DD];
    int tid = threadIdx.x;
    int wid = tid >> 6, d = tid & 63;
    int row = blockIdx.x * 4 + wid;
    float v = qin[row * DD + d] + att[row * DD + d];
    float m = waveSum(v) * (1.0f / 64.0f);
    float c = v - m;
    float var = waveSum(c * c) * (1.0f / 64.0f);
    float xv = (c / sqrtf(var + 1e-8f)) * g2[d] + b2ln[d];
    xs[wid][d] = xv;
    float a = b1v[d];
#pragma unroll 8
    for (int j = 0; j < DD; ++j) a = fmaf(xs[wid][j], W1T[j * DD + d], a);
    hs[wid][d] = fmaxf(a, 0.0f);
    float o = b2v[d];
#pragma unroll 8
    for (int j = 0; j < DD; ++j) o = fmaf(hs[wid][j], W2T[j * DD + d], o);
    float res = xv + o;
    if (log_ids[row] == 0) res = 0.0f;
    // --- final LN + logits ---
    float m2 = waveSum(res) * (1.0f / 64.0f);
    float c2 = res - m2;
    float var2 = waveSum(c2 * c2) * (1.0f / 64.0f);
    float f = (c2 / sqrtf(var2 + 1e-8f)) * lnf_g[d] + lnf_b[d];
    int pid = pos_ids[row];
    int nid = neg_ids[row];
    float p = waveSum(f * item_emb[pid * DD + d]);
    float n = waveSum(f * item_emb[nid * DD + d]);
    if (d == 0) {
        out[row] = p;
        out[BB * LLEN + row] = n;
    }
}

extern "C" void kernel_launch(void* const* d_in, const int* in_sizes, int n_in,
                              void* d_out, int out_size, void* d_ws, size_t ws_size,
                              hipStream_t stream) {
    const int* log_ids = (const int*)d_in[0];
    const int* log_times = (const int*)d_in[1];
    const int* pos_ids = (const int*)d_in[2];
    const int* neg_ids = (const int*)d_in[3];
    const float* item_emb = (const float*)d_in[4];
    const float* posK = (const float*)d_in[5];
    const float* posV = (const float*)d_in[6];
    const float* tK_emb = (const float*)d_in[7];
    const float* tV_emb = (const float*)d_in[8];
    const float* ln1_g = (const float*)d_in[9];
    const float* ln1_b = (const float*)d_in[10];
    const float* Wq = (const float*)d_in[11];
    const float* bq = (const float*)d_in[12];
    const float* Wk = (const float*)d_in[13];
    const float* bk = (const float*)d_in[14];
    const float* Wv = (const float*)d_in[15];
    const float* bv = (const float*)d_in[16];
    const float* ln2_g = (const float*)d_in[17];
    const float* ln2_b = (const float*)d_in[18];
    const float* W1 = (const float*)d_in[19];
    const float* b1 = (const float*)d_in[20];
    const float* W2 = (const float*)d_in[21];
    const float* b2 = (const float*)d_in[22];
    const float* lnf_g = (const float*)d_in[23];
    const float* lnf_b = (const float*)d_in[24];

    float* ws = (float*)d_ws;
    float* q = ws;                        // ln1 output (residual)
    float* Qb = q + BLD;
    float* Kb = Qb + BLD;
    float* Vb = Kb + BLD;
    float* att = Vb + BLD;
    float* wt = att + BLD;                // 10 x 64x64 transposed weights
    float* tKT = wt + 10 * DD * DD;       // [64][366]
    float* Qt = tKT + DD * TSPAN1;        // [6400][732]

    const int nrow = BB * LLEN;           // 6400

    const float* W1T0 = wt + 3 * DD * DD;
    const float* W2T0 = wt + 4 * DD * DD;
    const float* W1T1 = wt + 8 * DD * DD;
    const float* W2T1 = wt + 9 * DD * DD;

    transpose_kernel<<<11, 256, 0, stream>>>(Wq, Wk, Wv, W1, W2, tK_emb, wt, tKT);

    // layer 0 entry (embed fused)
    ln_qkv_kernel<<<nrow / 4, 256, 0, stream>>>(log_ids, item_emb,
                                                ln1_g, ln1_b,
                                                wt + 0 * DD * DD, bq,
                                                wt + 1 * DD * DD, bk,
                                                wt + 2 * DD * DD, bv,
                                                posK, posV,
                                                q, Qb, Kb, Vb);
    qt_kernel<<<nrow / 16, 384, 0, stream>>>(Qb, tKT, Qt);
    attn_kernel<<<BB * 50, 256, 0, stream>>>(Qb, Kb, Vb, log_times, Qt, tV_emb, att);

    // layer 0 tail + layer 1 entry
    mid_kernel<<<nrow / 4, 256, 0, stream>>>(q, att,
                                             ln2_g, ln2_b,
                                             W1T0, b1, W2T0, b2,
                                             log_ids,
                                             ln1_g + DD, ln1_b + DD,
                                             wt + 5 * DD * DD, bq + DD,
                                             wt + 6 * DD * DD, bk + DD,
                                             wt + 7 * DD * DD, bv + DD,
                                             posK, posV,
                                             q, Qb, Kb, Vb);
    qt_kernel<<<nrow / 16, 384, 0, stream>>>(Qb, tKT, Qt);
    attn_kernel<<<BB * 50, 256, 0, stream>>>(Qb, Kb, Vb, log_times, Qt, tV_emb, att);

    // layer 1 tail + final logits
    end_kernel<<<nrow / 4, 256, 0, stream>>>(q, att,
                                             ln2_g + DD, ln2_b + DD,
                                             W1T1, b1 + DD, W2T1, b2 + DD,
                                             log_ids,
                                             lnf_g, lnf_b, item_emb,
                                             pos_ids, neg_ids, (float*)d_out);
}

// Round 8
// 197.344 us; speedup vs baseline: 1.1390x; 1.0051x over previous
//
#include <hip/hip_runtime.h>
#include <math.h>

// TiSASRec forward on MI355X — round 7:
//  - attn: flash-style split-K — each query's key range split across 2 waves
//    (12800 waves, longest wave ~100 keys, uniform 201-key blocks);
//    local (m,l,partial-out) + exact combine after one barrier.
//    Qt row staged in LDS (shared by both halves).
//  - rest identical to R6 (MID/END fusion, transposed weights, Qt table).
// B=32, L=200, D=64, H=2, dh=32, NL=2.
#define BB 32
#define LLEN 200
#define DD 64
#define HH 2
#define NLAYER 2
#define BLD (BB * LLEN * DD)
#define TSPAN1 366   // TIME_SPAN+1

__device__ inline float waveSum(float v) {
#pragma unroll
    for (int off = 32; off > 0; off >>= 1) v += __shfl_xor(v, off);
    return v;
}
__device__ inline float halfSum(float v) {
    v += __shfl_xor(v, 1);
    v += __shfl_xor(v, 2);
    v += __shfl_xor(v, 4);
    v += __shfl_xor(v, 8);
    v += __shfl_xor(v, 16);
    return v;
}
__device__ inline float halfMax(float v) {
    v = fmaxf(v, __shfl_xor(v, 1));
    v = fmaxf(v, __shfl_xor(v, 2));
    v = fmaxf(v, __shfl_xor(v, 4));
    v = fmaxf(v, __shfl_xor(v, 8));
    v = fmaxf(v, __shfl_xor(v, 16));
    return v;
}

// grid=11: m<10 -> transpose 64x64 weights; m==10 -> tK_emb^T [64][366]
__global__ void transpose_kernel(const float* __restrict__ Wq,
                                 const float* __restrict__ Wk,
                                 const float* __restrict__ Wv,
                                 const float* __restrict__ W1,
                                 const float* __restrict__ W2,
                                 const float* __restrict__ tK_emb,
                                 float* __restrict__ wt,
                                 float* __restrict__ tKT) {
    int m = blockIdx.x;
    if (m < 10) {
        const float* src;
        switch (m % 5) {
            case 0: src = Wq; break;
            case 1: src = Wk; break;
            case 2: src = Wv; break;
            case 3: src = W1; break;
            default: src = W2; break;
        }
        src += (m / 5) * DD * DD;
        float* dst = wt + m * DD * DD;
        for (int e = threadIdx.x; e < DD * DD; e += 256) {
            int d = e >> 6, j = e & 63;
            dst[j * DD + d] = src[e];
        }
    } else {
        for (int e = threadIdx.x; e < TSPAN1 * DD; e += 256) {
            int t = e >> 6, d = e & 63;
            tKT[d * TSPAN1 + t] = tK_emb[e];
        }
    }
}

// Layer-0 entry: 4 rows/block, wave per row. Embedding gather fused.
__global__ void ln_qkv_kernel(const int* __restrict__ log_ids,
                              const float* __restrict__ item_emb,
                              const float* __restrict__ g,
                              const float* __restrict__ bln,
                              const float* __restrict__ WqT, const float* __restrict__ bq,
                              const float* __restrict__ WkT, const float* __restrict__ bk,
                              const float* __restrict__ WvT, const float* __restrict__ bv,
                              const float* __restrict__ posK,
                              const float* __restrict__ posV,
                              float* __restrict__ q,
                              float* __restrict__ Q, float* __restrict__ K,
                              float* __restrict__ V) {
    __shared__ float qs[4][DD], xs[4][DD];
    int tid = threadIdx.x;
    int wid = tid >> 6, d = tid & 63;
    int row = blockIdx.x * 4 + wid;
    int l = row % LLEN;
    int id = log_ids[row];
    float xv = (id == 0) ? 0.0f : item_emb[id * DD + d] * 8.0f;  // sqrt(64)*keep
    xs[wid][d] = xv;
    float m = waveSum(xv) * (1.0f / 64.0f);
    float c = xv - m;
    float var = waveSum(c * c) * (1.0f / 64.0f);
    float qv = (c / sqrtf(var + 1e-8f)) * g[d] + bln[d];
    qs[wid][d] = qv;
    q[row * DD + d] = qv;
    float aq = bq[d], ak = bk[d], av = bv[d];
#pragma unroll 8
    for (int j = 0; j < DD; ++j) {
        aq = fmaf(qs[wid][j], WqT[j * DD + d], aq);
        ak = fmaf(xs[wid][j], WkT[j * DD + d], ak);
        av = fmaf(xs[wid][j], WvT[j * DD + d], av);
    }
    Q[row * DD + d] = aq;
    K[row * DD + d] = ak + posK[l * DD + d];
    V[row * DD + d] = av + posV[l * DD + d];
}

// Qt[row][h*366+t] = sum_d Qh[row][h*32+d] * tK_emb[t][h*32+d]
__global__ void qt_kernel(const float* __restrict__ Q,
                          const float* __restrict__ tKT,
                          float* __restrict__ Qt_g) {
    __shared__ float Qs[16][DD];
    int tid = threadIdx.x;
    int base = blockIdx.x * 16;
    for (int e = tid; e < 16 * DD; e += 384)
        Qs[e >> 6][e & 63] = Q[(base + (e >> 6)) * DD + (e & 63)];
    __syncthreads();
    int t = tid;
    if (t < TSPAN1) {
        float acc[16];
#pragma unroll
        for (int gg = 0; gg < 16; ++gg) acc[gg] = 0.0f;
        for (int d = 0; d < 32; ++d) {
            float v = tKT[d * TSPAN1 + t];
#pragma unroll
            for (int gg = 0; gg < 16; ++gg) acc[gg] = fmaf(v, Qs[gg][d], acc[gg]);
        }
#pragma unroll
        for (int gg = 0; gg < 16; ++gg)
            Qt_g[(base + gg) * (2 * TSPAN1) + t] = acc[gg];
#pragma unroll
        for (int gg = 0; gg < 16; ++gg) acc[gg] = 0.0f;
        for (int d = 32; d < 64; ++d) {
            float v = tKT[d * TSPAN1 + t];
#pragma unroll
            for (int gg = 0; gg < 16; ++gg) acc[gg] = fmaf(v, Qs[gg][d], acc[gg]);
        }
#pragma unroll
        for (int gg = 0; gg < 16; ++gg)
            Qt_g[(base + gg) * (2 * TSPAN1) + TSPAN1 + t] = acc[gg];
    }
}

// Attention, split-K: block = pair {i,199-i} x 2 key-halves (4 waves).
// wid: qsel = wid>>1 (0: q=i, 1: q=199-i), half = wid&1.
// Each wave: scores + local unnormalized softmax + partial PV over its
// key range; exact combine after one barrier. grid = B*100.
__global__ void attn_kernel(const float* __restrict__ Q,
                            const float* __restrict__ Keff,
                            const float* __restrict__ Veff,
                            const int* __restrict__ log_times,
                            const float* __restrict__ Qt_g,
                            const float* __restrict__ tV_emb,
                            float* __restrict__ out) {
    __shared__ int t_s[LLEN];
    __shared__ float qt_s[2][2 * TSPAN1];
    __shared__ float sc[2][HH][LLEN];
    __shared__ unsigned short tm_s[2][LLEN];
    __shared__ float o_l[2][2][DD];
    __shared__ float ml_l[2][2][HH][2];   // [qsel][half][h][{m,l}]

    int tid = threadIdx.x;
    int wid = tid >> 6;
    int lane = tid & 63;
    int bi = blockIdx.x / 100;
    int i = blockIdx.x % 100;
    int qsel = wid >> 1, half = wid & 1;
    int qa = i, qb = 199 - i;
    int rowa = bi * LLEN + qa, rowb = bi * LLEN + qb;
    int qq = qsel ? qb : qa;
    int row = qsel ? rowb : rowa;
    int len = qq + 1;
    int mid = (((len + 1) >> 1) + 3) & ~3;
    if (mid > len) mid = len;
    int k_lo = half ? mid : 0;
    int k_hi = half ? len : mid;

    if (tid < LLEN) t_s[tid] = log_times[bi * LLEN + tid];
    for (int e = tid; e < 2 * 2 * TSPAN1; e += 256) {
        int qs_ = (e >= 2 * TSPAN1);
        int c = e - qs_ * 2 * TSPAN1;
        qt_s[qs_][c] = Qt_g[(qs_ ? rowb : rowa) * (2 * TSPAN1) + c];
    }
    __syncthreads();

    // bucket table for own range (read only by this wave)
    int tq = t_s[qq];
    for (int k = k_lo + lane; k < k_hi; k += 64) {
        int dt = tq - t_s[k];
        if (dt < 0) dt = -dt;
        tm_s[qsel][k] = (unsigned short)(int)fminf((float)dt * (1.0f / 86400.0f), 365.0f);
    }

    int h = lane >> 5;       // head
    int l5 = lane & 31;
    int cch = l5 >> 2;       // channel chunk 0..7
    int jo = l5 & 3;         // key offset in group
    float4 qv = ((const float4*)(Q + row * DD))[h * 8 + cch];
    const float4* K4 = (const float4*)(Keff + bi * LLEN * DD);
    const float* qtrow = &qt_s[qsel][h * TSPAN1];
    const float scale = 0.17677669529663687f;  // 1/sqrt(32)

    // phase 1: scores over [k_lo, k_hi), 4 keys per iteration
    for (int k0 = k_lo; k0 < k_hi; k0 += 4) {
        int k = k0 + jo;
        int kc = (k < k_hi) ? k : (k_hi - 1);
        int bucket = tm_s[qsel][kc];
        float4 kv = K4[kc * 16 + h * 8 + cch];
        float p = qv.x * kv.x + qv.y * kv.y + qv.z * kv.z + qv.w * kv.w;
        p += __shfl_xor(p, 4);
        p += __shfl_xor(p, 8);
        p += __shfl_xor(p, 16);   // full 32-dot for (h, key k)
        float s = (p + qtrow[bucket]) * scale;
        if (cch == 0 && k < k_hi) sc[qsel][h][k] = s;
    }

    // phase 2: LOCAL softmax pieces (unnormalized): m, exp, l
    float mloc = -INFINITY;
    for (int k = k_lo + l5; k < k_hi; k += 32) mloc = fmaxf(mloc, sc[qsel][h][k]);
    mloc = halfMax(mloc);
    float lloc = 0.0f;
    for (int k = k_lo + l5; k < k_hi; k += 32) {
        float e = expf(sc[qsel][h][k] - mloc);
        sc[qsel][h][k] = e;
        lloc += e;
    }
    lloc = halfSum(lloc);

    // phase 3: partial out over own range
    const float* Vb = Veff + bi * LLEN * DD + lane;
    const float* tVl = tV_emb + lane;
    float acc0 = 0.0f, acc1 = 0.0f, acc2 = 0.0f, acc3 = 0.0f;
    int k = k_lo;
    for (; k + 4 <= k_hi; k += 4) {
        int b0 = tm_s[qsel][k + 0];
        int b1 = tm_s[qsel][k + 1];
        int b2 = tm_s[qsel][k + 2];
        int b3 = tm_s[qsel][k + 3];
        float a0 = sc[qsel][h][k + 0];
        float a1 = sc[qsel][h][k + 1];
        float a2 = sc[qsel][h][k + 2];
        float a3 = sc[qsel][h][k + 3];
        acc0 = fmaf(a0, Vb[(k + 0) * DD] + tVl[b0 * DD], acc0);
        acc1 = fmaf(a1, Vb[(k + 1) * DD] + tVl[b1 * DD], acc1);
        acc2 = fmaf(a2, Vb[(k + 2) * DD] + tVl[b2 * DD], acc2);
        acc3 = fmaf(a3, Vb[(k + 3) * DD] + tVl[b3 * DD], acc3);
    }
    for (; k < k_hi; ++k) {
        int b0 = tm_s[qsel][k];
        acc0 = fmaf(sc[qsel][h][k], Vb[k * DD] + tVl[b0 * DD], acc0);
    }
    o_l[qsel][half][lane] = (acc0 + acc1) + (acc2 + acc3);
    if (l5 == 0) {
        ml_l[qsel][half][h][0] = mloc;
        ml_l[qsel][half][h][1] = lloc;
    }
    __syncthreads();

    // combine: wave 0 -> query a, wave 1 -> query b
    if (wid < 2) {
        int qs_ = wid;
        int r = qs_ ? rowb : rowa;
        int hh = lane >> 5;
        float m0 = ml_l[qs_][0][hh][0], l0 = ml_l[qs_][0][hh][1];
        float m1 = ml_l[qs_][1][hh][0], l1 = ml_l[qs_][1][hh][1];
        float M = fmaxf(m0, m1);
        float a0 = expf(m0 - M);     // -inf -> 0 for empty half
        float a1 = expf(m1 - M);
        float L = a0 * l0 + a1 * l1;
        float o = a0 * o_l[qs_][0][lane] + a1 * o_l[qs_][1][lane];
        out[r * DD + lane] = o / L;
    }
}

// MID: addln_ffn(layer i) fused with ln_qkv(layer i+1). 4 rows/block.
__global__ void mid_kernel(const float* __restrict__ qin,
                           const float* __restrict__ att,
                           const float* __restrict__ g2, const float* __restrict__ b2ln,
                           const float* __restrict__ W1T, const float* __restrict__ b1v,
                           const float* __restrict__ W2T, const float* __restrict__ b2v,
                           const int* __restrict__ log_ids,
                           const float* __restrict__ g1n, const float* __restrict__ b1n,
                           const float* __restrict__ WqT, const float* __restrict__ bq,
                           const float* __restrict__ WkT, const float* __restrict__ bk,
                           const float* __restrict__ WvT, const float* __restrict__ bv,
                           const float* __restrict__ posK,
                           const float* __restrict__ posV,
                           float* __restrict__ q,
                           float* __restrict__ Q, float* __restrict__ K,
                           float* __restrict__ V) {
    __shared__ float xs[4][DD], hs[4][DD], qs[4][DD];
    int tid = threadIdx.x;
    int wid = tid >> 6, d = tid & 63;
    int row = blockIdx.x * 4 + wid;
    int l = row % LLEN;
    // --- addln + FFN ---
    float v = qin[row * DD + d] + att[row * DD + d];
    float m = waveSum(v) * (1.0f / 64.0f);
    float c = v - m;
    float var = waveSum(c * c) * (1.0f / 64.0f);
    float xv = (c / sqrtf(var + 1e-8f)) * g2[d] + b2ln[d];
    xs[wid][d] = xv;
    float a = b1v[d];
#pragma unroll 8
    for (int j = 0; j < DD; ++j) a = fmaf(xs[wid][j], W1T[j * DD + d], a);
    hs[wid][d] = fmaxf(a, 0.0f);
    float o = b2v[d];
#pragma unroll 8
    for (int j = 0; j < DD; ++j) o = fmaf(hs[wid][j], W2T[j * DD + d], o);
    float res = xv + o;
    if (log_ids[row] == 0) res = 0.0f;
    // --- next layer: LN1 + QKV projection ---
    float m2 = waveSum(res) * (1.0f / 64.0f);
    float c2 = res - m2;
    float var2 = waveSum(c2 * c2) * (1.0f / 64.0f);
    float qv = (c2 / sqrtf(var2 + 1e-8f)) * g1n[d] + b1n[d];
    qs[wid][d] = qv;
    xs[wid][d] = res;
    q[row * DD + d] = qv;
    float aq = bq[d], ak = bk[d], av = bv[d];
#pragma unroll 8
    for (int j = 0; j < DD; ++j) {
        aq = fmaf(qs[wid][j], WqT[j * DD + d], aq);
        ak = fmaf(xs[wid][j], WkT[j * DD + d], ak);
        av = fmaf(xs[wid][j], WvT[j * DD + d], av);
    }
    Q[row * DD + d] = aq;
    K[row * DD + d] = ak + posK[l * DD + d];
    V[row * DD + d] = av + posV[l * DD + d];
}

// END: addln_ffn(last layer) fused with final LN + logits. 4 rows/block.
__global__ void end_kernel(const float* __restrict__ qin,
                           const float* __restrict__ att,
                           const float* __restrict__ g2, const float* __restrict__ b2ln,
                           const float* __restrict__ W1T, const float* __restrict__ b1v,
                           const float* __restrict__ W2T, const float* __restrict__ b2v,
                           const int* __restrict__ log_ids,
                           const float* __restrict__ lnf_g, const float* __restrict__ lnf_b,
                           const float* __restrict__ item_emb,
                           const int* __restrict__ pos_ids,
                           const int* __restrict__ neg_ids,
                           float* __restrict__ out) {
    __shared__ float xs[4][DD], hs[4][DD];
    int tid = threadIdx.x;
    int wid = tid >> 6, d = tid & 63;
    int row = blockIdx.x * 4 + wid;
    float v = qin[row * DD + d] + att[row * DD + d];
    float m = waveSum(v) * (1.0f / 64.0f);
    float c = v - m;
    float var = waveSum(c * c) * (1.0f / 64.0f);
    float xv = (c / sqrtf(var + 1e-8f)) * g2[d] + b2ln[d];
    xs[wid][d] = xv;
    float a = b1v[d];
#pragma unroll 8
    for (int j = 0; j < DD; ++j) a = fmaf(xs[wid][j], W1T[j * DD + d], a);
    hs[wid][d] = fmaxf(a, 0.0f);
    float o = b2v[d];
#pragma unroll 8
    for (int j = 0; j < DD; ++j) o = fmaf(hs[wid][j], W2T[j * DD + d], o);
    float res = xv + o;
    if (log_ids[row] == 0) res = 0.0f;
    // --- final LN + logits ---
    float m2 = waveSum(res) * (1.0f / 64.0f);
    float c2 = res - m2;
    float var2 = waveSum(c2 * c2) * (1.0f / 64.0f);
    float f = (c2 / sqrtf(var2 + 1e-8f)) * lnf_g[d] + lnf_b[d];
    int pid = pos_ids[row];
    int nid = neg_ids[row];
    float p = waveSum(f * item_emb[pid * DD + d]);
    float n = waveSum(f * item_emb[nid * DD + d]);
    if (d == 0) {
        out[row] = p;
        out[BB * LLEN + row] = n;
    }
}

extern "C" void kernel_launch(void* const* d_in, const int* in_sizes, int n_in,
                              void* d_out, int out_size, void* d_ws, size_t ws_size,
                              hipStream_t stream) {
    const int* log_ids = (const int*)d_in[0];
    const int* log_times = (const int*)d_in[1];
    const int* pos_ids = (const int*)d_in[2];
    const int* neg_ids = (const int*)d_in[3];
    const float* item_emb = (const float*)d_in[4];
    const float* posK = (const float*)d_in[5];
    const float* posV = (const float*)d_in[6];
    const float* tK_emb = (const float*)d_in[7];
    const float* tV_emb = (const float*)d_in[8];
    const float* ln1_g = (const float*)d_in[9];
    const float* ln1_b = (const float*)d_in[10];
    const float* Wq = (const float*)d_in[11];
    const float* bq = (const float*)d_in[12];
    const float* Wk = (const float*)d_in[13];
    const float* bk = (const float*)d_in[14];
    const float* Wv = (const float*)d_in[15];
    const float* bv = (const float*)d_in[16];
    const float* ln2_g = (const float*)d_in[17];
    const float* ln2_b = (const float*)d_in[18];
    const float* W1 = (const float*)d_in[19];
    const float* b1 = (const float*)d_in[20];
    const float* W2 = (const float*)d_in[21];
    const float* b2 = (const float*)d_in[22];
    const float* lnf_g = (const float*)d_in[23];
    const float* lnf_b = (const float*)d_in[24];

    float* ws = (float*)d_ws;
    float* q = ws;                        // ln1 output (residual)
    float* Qb = q + BLD;
    float* Kb = Qb + BLD;
    float* Vb = Kb + BLD;
    float* att = Vb + BLD;
    float* wt = att + BLD;                // 10 x 64x64 transposed weights
    float* tKT = wt + 10 * DD * DD;       // [64][366]
    float* Qt = tKT + DD * TSPAN1;        // [6400][732]

    const int nrow = BB * LLEN;           // 6400

    const float* W1T0 = wt + 3 * DD * DD;
    const float* W2T0 = wt + 4 * DD * DD;
    const float* W1T1 = wt + 8 * DD * DD;
    const float* W2T1 = wt + 9 * DD * DD;

    transpose_kernel<<<11, 256, 0, stream>>>(Wq, Wk, Wv, W1, W2, tK_emb, wt, tKT);

    // layer 0 entry (embed fused)
    ln_qkv_kernel<<<nrow / 4, 256, 0, stream>>>(log_ids, item_emb,
                                                ln1_g, ln1_b,
                                                wt + 0 * DD * DD, bq,
                                                wt + 1 * DD * DD, bk,
                                                wt + 2 * DD * DD, bv,
                                                posK, posV,
                                                q, Qb, Kb, Vb);
    qt_kernel<<<nrow / 16, 384, 0, stream>>>(Qb, tKT, Qt);
    attn_kernel<<<BB * 100, 256, 0, stream>>>(Qb, Kb, Vb, log_times, Qt, tV_emb, att);

    // layer 0 tail + layer 1 entry
    mid_kernel<<<nrow / 4, 256, 0, stream>>>(q, att,
                                             ln2_g, ln2_b,
                                             W1T0, b1, W2T0, b2,
                                             log_ids,
                                             ln1_g + DD, ln1_b + DD,
                                             wt + 5 * DD * DD, bq + DD,
                                             wt + 6 * DD * DD, bk + DD,
                                             wt + 7 * DD * DD, bv + DD,
                                             posK, posV,
                                             q, Qb, Kb, Vb);
    qt_kernel<<<nrow / 16, 384, 0, stream>>>(Qb, tKT, Qt);
    attn_kernel<<<BB * 100, 256, 0, stream>>>(Qb, Kb, Vb, log_times, Qt, tV_emb, att);

    // layer 1 tail + final logits
    end_kernel<<<nrow / 4, 256, 0, stream>>>(q, att,
                                             ln2_g + DD, ln2_b + DD,
                                             W1T1, b1 + DD, W2T1, b2 + DD,
                                             log_ids,
                                             lnf_g, lnf_b, item_emb,
                                             pos_ids, neg_ids, (float*)d_out);
}